// Round 5
// baseline (1803.986 us; speedup 1.0000x reference)
//
#include <hip/hip_runtime.h>
#include <hip/hip_bf16.h>
#include <hip/hip_fp16.h>

typedef _Float16 f16x8 __attribute__((ext_vector_type(8)));
typedef _Float16 f16x4 __attribute__((ext_vector_type(4)));
typedef float f32x4 __attribute__((ext_vector_type(4)));

static __device__ __forceinline__ float fast_sigmoid(float x) {
  return __builtin_amdgcn_rcpf(1.f + __expf(-x));
}
static __device__ __forceinline__ float fast_tanh(float x) {
  return 1.f - 2.f * __builtin_amdgcn_rcpf(__expf(2.f * x) + 1.f);
}

// ---------------------------------------------------------------------------
// Generic fp32 GEMM with fused bias + activation epilogue.
// C[M,N] = act(A[M,K] @ W[N,K]^T + bias)
// MODE 0: val + b0[n] + b1[n]; MODE 1: relu(val + b0[n]); MODE 2: tanh(val + b0[n])
// ---------------------------------------------------------------------------
template<int BM, int BN, int BK, int TM, int TN, int MODE>
__global__ __launch_bounds__(256) void gemm_bias_act(
    const float* __restrict__ A, const float* __restrict__ W,
    const float* __restrict__ b0, const float* __restrict__ b1,
    float* __restrict__ C, int M, int N, int K) {
  static_assert(BM == BN, "loader assumes square tile");
  static_assert(BM * BK == 1024, "one float4 per thread");
  __shared__ float As[BK][BM];
  __shared__ float Ws[BK][BN];
  const int tid = threadIdx.x;
  const int m0 = blockIdx.x * BM, n0 = blockIdx.y * BN;
  constexpr int KQ = BK / 4;
  const int lm = tid / KQ;
  const int lk = (tid % KQ) * 4;
  const int tx = tid % (BN / TN);
  const int ty = tid / (BN / TN);
  float acc[TM][TN] = {};

  for (int k0 = 0; k0 < K; k0 += BK) {
    float4 av = *reinterpret_cast<const float4*>(A + (size_t)(m0 + lm) * K + k0 + lk);
    float4 wv = *reinterpret_cast<const float4*>(W + (size_t)(n0 + lm) * K + k0 + lk);
    As[lk + 0][lm] = av.x; As[lk + 1][lm] = av.y; As[lk + 2][lm] = av.z; As[lk + 3][lm] = av.w;
    Ws[lk + 0][lm] = wv.x; Ws[lk + 1][lm] = wv.y; Ws[lk + 2][lm] = wv.z; Ws[lk + 3][lm] = wv.w;
    __syncthreads();
#pragma unroll
    for (int k = 0; k < BK; ++k) {
      float a[TM], b[TN];
#pragma unroll
      for (int i = 0; i < TM / 4; ++i)
        *reinterpret_cast<float4*>(&a[i * 4]) =
            *reinterpret_cast<const float4*>(&As[k][ty * TM + i * 4]);
#pragma unroll
      for (int i = 0; i < TN / 4; ++i)
        *reinterpret_cast<float4*>(&b[i * 4]) =
            *reinterpret_cast<const float4*>(&Ws[k][tx * TN + i * 4]);
#pragma unroll
      for (int i = 0; i < TM; ++i)
#pragma unroll
        for (int jj = 0; jj < TN; ++jj) acc[i][jj] += a[i] * b[jj];
    }
    __syncthreads();
  }

#pragma unroll
  for (int i = 0; i < TM; ++i) {
    const int m = m0 + ty * TM + i;
#pragma unroll
    for (int jq = 0; jq < TN / 4; ++jq) {
      float4 v;
      float* vp = &v.x;
#pragma unroll
      for (int u = 0; u < 4; ++u) {
        const int n = n0 + tx * TN + jq * 4 + u;
        float val = acc[i][jq * 4 + u];
        if (MODE == 0) {
          val += b0[n] + b1[n];
        } else if (MODE == 1) {
          val = fmaxf(val + b0[n], 0.f);
        } else {
          val = fast_tanh(val + b0[n]);
        }
        vp[u] = val;
      }
      *reinterpret_cast<float4*>(C + (size_t)m * N + n0 + tx * TN + jq * 4) = v;
    }
  }
}

// ---------------------------------------------------------------------------
// LSTM recurrence, v5 (MFMA-batched). Grid (4 batch-tiles, 2 dirs) = 8 wgs,
// 512 threads = 8 waves. Per step: G[16,512] = Whh[512,128] @ h[16,128]^T
// via v_mfma_f32_16x16x32_f16.
//   A = Whh (f16, in VGPRs): wave w owns M-frags {g*8+w} -> gates
//       g*128 + w*16 .. +15. Lane supplies A[m=l&15][k=kf*32+(l>>4)*8+j].
//   B = h^T (f16, LDS [16][272B] padded rows, double-buffered):
//       lane reads h[b=l&15][kf*32+(l>>4)*8 ..+7] = one ds_read_b128.
//   D: col=l&15=batch, row=(l>>4)*4+r -> unit u = w*16+q*4+r; all 4 gates
//       of (b,u) land in the same lane -> gate math in-register, c in VGPRs.
// h written back as contiguous f16x4; out written as float4. One barrier
// per step (write buffer != read buffer).
// ---------------------------------------------------------------------------
__global__ __launch_bounds__(512, 2) void lstm_mfma(
    const float* __restrict__ xg_f, const float* __restrict__ xg_b,
    const float* __restrict__ Whh_f, const float* __restrict__ Whh_b,
    float* __restrict__ out) {
  const int bt = blockIdx.x;       // batch tile: batches bt*16 .. +15
  const int dir = blockIdx.y;
  const int tid = threadIdx.x;
  const int w = tid >> 6;          // wave 0..7 -> units w*16 .. +15
  const int l = tid & 63;
  const int col = l & 15;          // batch-within-tile (B and D col)
  const int q = l >> 4;            // lane quad-group 0..3

  const float* __restrict__ xg  = dir ? xg_b : xg_f;
  const float* __restrict__ Whh = dir ? Whh_b : Whh_f;

  __shared__ __align__(16) unsigned char h_lds[2][16][272];

  // ---- A-frags of Whh (held in VGPRs for the whole kernel) ----
  f16x8 a[4][4];
#pragma unroll
  for (int g = 0; g < 4; ++g) {
    const int gate = (g * 8 + w) * 16 + col;
#pragma unroll
    for (int kf = 0; kf < 4; ++kf) {
      const float* p = Whh + (size_t)gate * 128 + kf * 32 + q * 8;
      float4 v0 = *reinterpret_cast<const float4*>(p);
      float4 v1 = *reinterpret_cast<const float4*>(p + 4);
      f16x8 av;
      av[0] = (_Float16)v0.x; av[1] = (_Float16)v0.y;
      av[2] = (_Float16)v0.z; av[3] = (_Float16)v0.w;
      av[4] = (_Float16)v1.x; av[5] = (_Float16)v1.y;
      av[6] = (_Float16)v1.z; av[7] = (_Float16)v1.w;
      a[g][kf] = av;
    }
  }

  for (int i = tid; i < (int)(sizeof(h_lds) / 4); i += 512)
    reinterpret_cast<unsigned int*>(h_lds)[i] = 0u;
  f32x4 c4 = {0.f, 0.f, 0.f, 0.f};
  __syncthreads();

  const int tt0 = dir ? 511 : 0;
  const int stp = dir ? -1 : 1;
  const int b_glob = bt * 16 + col;
  const size_t xbase = (size_t)b_glob * 512 * 512;  // xg[b][t][512]
  const int goff = w * 16 + q * 4;                  // unit base for this lane

  f32x4 xv[4], xn[4];
#pragma unroll
  for (int g = 0; g < 4; ++g)
    xv[g] = *reinterpret_cast<const f32x4*>(
        xg + xbase + (size_t)tt0 * 512 + g * 128 + goff);

  for (int t = 0; t < 512; ++t) {
    const int tt = tt0 + stp * t;

    // B-frags from LDS (one ds_read_b128 each)
    f16x8 bf[4];
#pragma unroll
    for (int kf = 0; kf < 4; ++kf)
      bf[kf] = *reinterpret_cast<const f16x8*>(
          &h_lds[t & 1][col][(kf * 32 + q * 8) * 2]);

    // prefetch next step's xg (overlaps MFMA chain)
#pragma unroll
    for (int g = 0; g < 4; ++g) xn[g] = xv[g];
    if (t + 1 < 512) {
#pragma unroll
      for (int g = 0; g < 4; ++g)
        xn[g] = *reinterpret_cast<const f32x4*>(
            xg + xbase + (size_t)(tt + stp) * 512 + g * 128 + goff);
    }

    f32x4 acc[4] = {{0.f,0.f,0.f,0.f},{0.f,0.f,0.f,0.f},
                    {0.f,0.f,0.f,0.f},{0.f,0.f,0.f,0.f}};
#pragma unroll
    for (int kf = 0; kf < 4; ++kf) {
#pragma unroll
      for (int g = 0; g < 4; ++g)
        acc[g] = __builtin_amdgcn_mfma_f32_16x16x32_f16(a[g][kf], bf[kf], acc[g], 0, 0, 0);
    }

    // gates + state update (all in-register; element r -> unit goff+r)
    f16x4 hpack;
    float hout[4];
#pragma unroll
    for (int r = 0; r < 4; ++r) {
      const float gi = fast_sigmoid(acc[0][r] + xv[0][r]);
      const float gf = fast_sigmoid(acc[1][r] + xv[1][r]);
      const float gg = fast_tanh(acc[2][r] + xv[2][r]);
      const float go = fast_sigmoid(acc[3][r] + xv[3][r]);
      c4[r] = gf * c4[r] + gi * gg;
      const float h = go * fast_tanh(c4[r]);
      hpack[r] = (_Float16)h;
      hout[r] = h;
    }

    // h -> next LDS buffer (contiguous f16x4, 8B aligned)
    *reinterpret_cast<f16x4*>(&h_lds[(t + 1) & 1][col][goff * 2]) = hpack;

    // h -> global out (float4, layout [b][t][256] with dir offset)
    *reinterpret_cast<float4*>(out + ((size_t)b_glob * 512 + tt) * 256 + dir * 128 + goff)
        = make_float4(hout[0], hout[1], hout[2], hout[3]);

#pragma unroll
    for (int g = 0; g < 4; ++g) xv[g] = xn[g];
    __syncthreads();
  }
}

// ---------------------------------------------------------------------------
// Launcher
// ---------------------------------------------------------------------------
extern "C" void kernel_launch(void* const* d_in, const int* in_sizes, int n_in,
                              void* d_out, int out_size, void* d_ws, size_t ws_size,
                              hipStream_t stream) {
  (void)in_sizes; (void)n_in; (void)out_size; (void)ws_size;

  const float* x     = (const float*)d_in[0];
  const float* Wih00 = (const float*)d_in[1];
  const float* Whh00 = (const float*)d_in[2];
  const float* bih00 = (const float*)d_in[3];
  const float* bhh00 = (const float*)d_in[4];
  const float* Wih01 = (const float*)d_in[5];
  const float* Whh01 = (const float*)d_in[6];
  const float* bih01 = (const float*)d_in[7];
  const float* bhh01 = (const float*)d_in[8];
  const float* Wih10 = (const float*)d_in[9];
  const float* Whh10 = (const float*)d_in[10];
  const float* bih10 = (const float*)d_in[11];
  const float* bhh10 = (const float*)d_in[12];
  const float* Wih11 = (const float*)d_in[13];
  const float* Whh11 = (const float*)d_in[14];
  const float* bih11 = (const float*)d_in[15];
  const float* bhh11 = (const float*)d_in[16];
  const float* W1 = (const float*)d_in[17];
  const float* b1 = (const float*)d_in[18];
  const float* W2 = (const float*)d_in[19];
  const float* b2 = (const float*)d_in[20];
  float* out = (float*)d_out;

  char* ws = (char*)d_ws;
  float* xg_fw = (float*)ws;                          // 64 MB  [B,T,512]
  float* xg_bw = (float*)(ws + ((size_t)64 << 20));   // 64 MB  [B,T,512]
  float* buf   = (float*)(ws + ((size_t)128 << 20));  // 32 MB  [B,T,256]

  const int M = 64 * 512;  // 32768 rows

  // ---- layer 0 ----
  gemm_bias_act<128, 128, 8, 8, 8, 0><<<dim3(M / 128, 4), 256, 0, stream>>>(
      x, Wih00, bih00, bhh00, xg_fw, M, 512, 64);
  gemm_bias_act<128, 128, 8, 8, 8, 0><<<dim3(M / 128, 4), 256, 0, stream>>>(
      x, Wih01, bih01, bhh01, xg_bw, M, 512, 64);
  lstm_mfma<<<dim3(4, 2), 512, 0, stream>>>(xg_fw, xg_bw, Whh00, Whh01, buf);

  // ---- layer 1 ----
  gemm_bias_act<128, 128, 8, 8, 8, 0><<<dim3(M / 128, 4), 256, 0, stream>>>(
      buf, Wih10, bih10, bhh10, xg_fw, M, 512, 256);
  gemm_bias_act<128, 128, 8, 8, 8, 0><<<dim3(M / 128, 4), 256, 0, stream>>>(
      buf, Wih11, bih11, bhh11, xg_bw, M, 512, 256);
  lstm_mfma<<<dim3(4, 2), 512, 0, stream>>>(xg_fw, xg_bw, Whh10, Whh11, buf);

  // ---- head ----
  gemm_bias_act<128, 128, 8, 8, 8, 1><<<dim3(M / 128, 2), 256, 0, stream>>>(
      buf, W1, b1, nullptr, xg_fw, M, 256, 256);
  gemm_bias_act<64, 64, 16, 4, 4, 2><<<dim3(M / 64, 1), 256, 0, stream>>>(
      xg_fw, W2, b2, nullptr, out, M, 64, 256);
}

// Round 6
// 778.052 us; speedup vs baseline: 2.3186x; 2.3186x over previous
//
#include <hip/hip_runtime.h>
#include <hip/hip_bf16.h>
#include <hip/hip_fp16.h>

typedef _Float16 h2vec __attribute__((ext_vector_type(2)));
typedef _Float16 f16x8 __attribute__((ext_vector_type(8)));
typedef float f32x4 __attribute__((ext_vector_type(4)));

static __device__ __forceinline__ float fast_sigmoid(float x) {
  return __builtin_amdgcn_rcpf(1.f + __expf(-x));
}
static __device__ __forceinline__ float fast_tanh(float x) {
  return 1.f - 2.f * __builtin_amdgcn_rcpf(__expf(2.f * x) + 1.f);
}
static __device__ __forceinline__ float fdot2u(unsigned int a, unsigned int b, float c) {
#if __has_builtin(__builtin_amdgcn_fdot2)
  return __builtin_amdgcn_fdot2(__builtin_bit_cast(h2vec, a),
                                __builtin_bit_cast(h2vec, b), c, false);
#else
  h2vec av = __builtin_bit_cast(h2vec, a);
  h2vec bv = __builtin_bit_cast(h2vec, b);
  return c + (float)av[0] * (float)bv[0] + (float)av[1] * (float)bv[1];
#endif
}
template<int CTRL>
static __device__ __forceinline__ float dpp_add(float v) {
  int x = __builtin_bit_cast(int, v);
  int y = __builtin_amdgcn_update_dpp(0, x, CTRL, 0xF, 0xF, true);
  return v + __builtin_bit_cast(float, y);
}

// ---------------------------------------------------------------------------
// f16-MFMA GEMM with fused f32->f16 staging and bias+activation epilogue.
// C[M,N] = act(A[M,K] @ W[N,K]^T + bias),  A,W,C fp32 in HBM.
// Tile: BM=128, BN=64, BK=64. 256 threads = 4 waves (2x2), wave sub-tile
// 64x32 = 4x2 frags of 16x16, K chained via v_mfma_f32_16x16x32_f16.
// LDS rows are 64 f16 = 128B with XOR swizzle (byte ^= (row&7)<<4) so both
// staging writes and frag reads are 2-way-or-better (free) on the banks.
// MODE 0: val + b0[n] + b1[n]; MODE 1: relu(val + b0[n]); MODE 2: tanh(val + b0[n])
// Requires: M%128==0, N%64==0, K%64==0.
// ---------------------------------------------------------------------------
template<int MODE>
__global__ __launch_bounds__(256) void gemm_mfma(
    const float* __restrict__ A, const float* __restrict__ W,
    const float* __restrict__ b0, const float* __restrict__ b1,
    float* __restrict__ C, int M, int N, int K) {
  __shared__ __align__(16) unsigned char As[128 * 128];  // 128 rows x 128B
  __shared__ __align__(16) unsigned char Bs[64 * 128];   // 64 rows x 128B
  const int tid = threadIdx.x;
  const int wave = tid >> 6, l = tid & 63;
  const int wm = wave >> 1, wn = wave & 1;
  const int m0 = blockIdx.x * 128, n0 = blockIdx.y * 64;
  const int lrow = l & 15, lq = l >> 4;

  f32x4 acc[4][2] = {};

  const int arow = tid >> 1, akc = (tid & 1) * 32;   // A loader: 32 f32/thread
  const int brow = tid >> 2, bkc = (tid & 3) * 16;   // B loader: 16 f32/thread

  for (int k0 = 0; k0 < K; k0 += 64) {
    // ---- stage A tile (128x64) as f16, swizzled ----
    {
      const float* src = A + (size_t)(m0 + arow) * K + k0 + akc;
#pragma unroll
      for (int u = 0; u < 4; ++u) {
        float4 v0 = *reinterpret_cast<const float4*>(src + u * 8);
        float4 v1 = *reinterpret_cast<const float4*>(src + u * 8 + 4);
        f16x8 h;
        h[0] = (_Float16)v0.x; h[1] = (_Float16)v0.y;
        h[2] = (_Float16)v0.z; h[3] = (_Float16)v0.w;
        h[4] = (_Float16)v1.x; h[5] = (_Float16)v1.y;
        h[6] = (_Float16)v1.z; h[7] = (_Float16)v1.w;
        const int kbyte = (akc + u * 8) * 2;
        *reinterpret_cast<f16x8*>(&As[arow * 128 + (kbyte ^ ((arow & 7) << 4))]) = h;
      }
    }
    // ---- stage B tile (64x64) as f16, swizzled ----
    {
      const float* src = W + (size_t)(n0 + brow) * K + k0 + bkc;
#pragma unroll
      for (int u = 0; u < 2; ++u) {
        float4 v0 = *reinterpret_cast<const float4*>(src + u * 8);
        float4 v1 = *reinterpret_cast<const float4*>(src + u * 8 + 4);
        f16x8 h;
        h[0] = (_Float16)v0.x; h[1] = (_Float16)v0.y;
        h[2] = (_Float16)v0.z; h[3] = (_Float16)v0.w;
        h[4] = (_Float16)v1.x; h[5] = (_Float16)v1.y;
        h[6] = (_Float16)v1.z; h[7] = (_Float16)v1.w;
        const int kbyte = (bkc + u * 8) * 2;
        *reinterpret_cast<f16x8*>(&Bs[brow * 128 + (kbyte ^ ((brow & 7) << 4))]) = h;
      }
    }
    __syncthreads();

#pragma unroll
    for (int kk = 0; kk < 64; kk += 32) {
      const int kbyte = (kk + lq * 8) * 2;
      f16x8 af[4], bf[2];
#pragma unroll
      for (int mt = 0; mt < 4; ++mt) {
        const int row = wm * 64 + mt * 16 + lrow;
        af[mt] = *reinterpret_cast<const f16x8*>(
            &As[row * 128 + (kbyte ^ ((row & 7) << 4))]);
      }
#pragma unroll
      for (int nt = 0; nt < 2; ++nt) {
        const int row = wn * 32 + nt * 16 + lrow;
        bf[nt] = *reinterpret_cast<const f16x8*>(
            &Bs[row * 128 + (kbyte ^ ((row & 7) << 4))]);
      }
#pragma unroll
      for (int mt = 0; mt < 4; ++mt)
#pragma unroll
        for (int nt = 0; nt < 2; ++nt)
          acc[mt][nt] = __builtin_amdgcn_mfma_f32_16x16x32_f16(
              af[mt], bf[nt], acc[mt][nt], 0, 0, 0);
    }
    __syncthreads();
  }

  // ---- epilogue: D row = lq*4+r (m), col = lrow (n) ----
#pragma unroll
  for (int nt = 0; nt < 2; ++nt) {
    const int n = n0 + wn * 32 + nt * 16 + lrow;
    float bias = 0.f;
    if (MODE == 0) bias = b0[n] + b1[n];
    else bias = b0[n];
#pragma unroll
    for (int mt = 0; mt < 4; ++mt) {
#pragma unroll
      for (int r = 0; r < 4; ++r) {
        const int m = m0 + wm * 64 + mt * 16 + lq * 4 + r;
        float val = acc[mt][nt][r] + bias;
        if (MODE == 1) val = fmaxf(val, 0.f);
        if (MODE == 2) val = fast_tanh(val);
        C[(size_t)m * N + n] = val;
      }
    }
  }
}

// ---------------------------------------------------------------------------
// LSTM recurrence (v2, proven 313 us/layer). One 256-thread block per
// (batch, direction). Thread (j2 = tid>>2, kq = tid&3) computes 8 gate-rows
// {g*128 + 2*j2 + u} over k-quarter [kq*32, +32), weights as f16x2 in VGPRs.
// h in LDS as f16x2 (bank-disjoint padded chunks, double-buffered, one
// barrier/step). Quad DPP butterfly reduces partials. Dots via v_dot2_f32_f16.
// ---------------------------------------------------------------------------
__global__ __launch_bounds__(256, 1) void lstm_seq2(
    const float* __restrict__ xg_f, const float* __restrict__ xg_b,
    const float* __restrict__ Whh_f, const float* __restrict__ Whh_b,
    float* __restrict__ out) {
  const int b = blockIdx.x;
  const int dir = blockIdx.y;
  const int tid = threadIdx.x;
  const int j2 = tid >> 2;  // 0..63 unit pair
  const int kq = tid & 3;   // k quarter
  const float* __restrict__ xg  = dir ? xg_b : xg_f;
  const float* __restrict__ Whh = dir ? Whh_b : Whh_f;

  __shared__ unsigned int hbuf[2][80];  // [buf][chunk*20 + dword], f16x2 h

  unsigned int w[4][2][16];
#pragma unroll
  for (int g = 0; g < 4; ++g)
#pragma unroll
    for (int u = 0; u < 2; ++u) {
      const float4* wr = reinterpret_cast<const float4*>(
          Whh + (size_t)(g * 128 + 2 * j2 + u) * 128 + kq * 32);
#pragma unroll
      for (int q = 0; q < 8; ++q) {
        float4 v = wr[q];
        __half2 p0 = __floats2half2_rn(v.x, v.y);
        __half2 p1 = __floats2half2_rn(v.z, v.w);
        w[g][u][2 * q]     = __builtin_bit_cast(unsigned int, p0);
        w[g][u][2 * q + 1] = __builtin_bit_cast(unsigned int, p1);
      }
    }

  if (tid < 160) reinterpret_cast<unsigned int*>(hbuf)[tid] = 0u;
  float c0 = 0.f, c1 = 0.f;
  __syncthreads();

  const int tt0 = dir ? 511 : 0;
  const int stp = dir ? -1 : 1;
  const size_t base = (size_t)b * 512 * 512;
  const int xoff = kq * 128 + 2 * j2;
  const bool writer = (kq == (j2 >> 4));
  const int wdst = (j2 >> 4) * 20 + (j2 & 15);

  float2 xv = *reinterpret_cast<const float2*>(xg + base + (size_t)tt0 * 512 + xoff);

  for (int t = 0; t < 512; ++t) {
    const int tt = tt0 + stp * t;

    const unsigned int* hc = &hbuf[t & 1][kq * 20];
    uint4 q0 = reinterpret_cast<const uint4*>(hc)[0];
    uint4 q1 = reinterpret_cast<const uint4*>(hc)[1];
    uint4 q2 = reinterpret_cast<const uint4*>(hc)[2];
    uint4 q3 = reinterpret_cast<const uint4*>(hc)[3];
    unsigned int ha[16];
    ha[0] = q0.x; ha[1] = q0.y; ha[2] = q0.z; ha[3] = q0.w;
    ha[4] = q1.x; ha[5] = q1.y; ha[6] = q1.z; ha[7] = q1.w;
    ha[8] = q2.x; ha[9] = q2.y; ha[10] = q2.z; ha[11] = q2.w;
    ha[12] = q3.x; ha[13] = q3.y; ha[14] = q3.z; ha[15] = q3.w;

    float2 xn = make_float2(0.f, 0.f);
    if (t + 1 < 512)
      xn = *reinterpret_cast<const float2*>(xg + base + (size_t)(tt + stp) * 512 + xoff);

    float acc[4][2];
#pragma unroll
    for (int g = 0; g < 4; ++g) {
      acc[g][0] = (g == kq) ? xv.x : 0.f;
      acc[g][1] = (g == kq) ? xv.y : 0.f;
    }
#pragma unroll
    for (int kk = 0; kk < 16; ++kk) {
#pragma unroll
      for (int g = 0; g < 4; ++g) {
        acc[g][0] = fdot2u(w[g][0][kk], ha[kk], acc[g][0]);
        acc[g][1] = fdot2u(w[g][1][kk], ha[kk], acc[g][1]);
      }
    }
#pragma unroll
    for (int g = 0; g < 4; ++g)
#pragma unroll
      for (int u = 0; u < 2; ++u) {
        float a = acc[g][u];
        a = dpp_add<0xB1>(a);  // xor 1
        a = dpp_add<0x4E>(a);  // xor 2
        acc[g][u] = a;
      }

    const float i0 = fast_sigmoid(acc[0][0]), i1 = fast_sigmoid(acc[0][1]);
    const float f0 = fast_sigmoid(acc[1][0]), f1 = fast_sigmoid(acc[1][1]);
    const float g0 = fast_tanh(acc[2][0]),    g1 = fast_tanh(acc[2][1]);
    const float o0 = fast_sigmoid(acc[3][0]), o1 = fast_sigmoid(acc[3][1]);
    c0 = f0 * c0 + i0 * g0;
    c1 = f1 * c1 + i1 * g1;
    const float h0 = o0 * fast_tanh(c0);
    const float h1 = o1 * fast_tanh(c1);

    if (writer) {
      __half2 hp = __floats2half2_rn(h0, h1);
      hbuf[(t + 1) & 1][wdst] = __builtin_bit_cast(unsigned int, hp);
      *reinterpret_cast<float2*>(out + ((size_t)b * 512 + tt) * 256 + dir * 128 + 2 * j2)
          = make_float2(h0, h1);
    }
    xv = xn;
    __syncthreads();
  }
}

// ---------------------------------------------------------------------------
// Launcher
// ---------------------------------------------------------------------------
extern "C" void kernel_launch(void* const* d_in, const int* in_sizes, int n_in,
                              void* d_out, int out_size, void* d_ws, size_t ws_size,
                              hipStream_t stream) {
  (void)in_sizes; (void)n_in; (void)out_size; (void)ws_size;

  const float* x     = (const float*)d_in[0];
  const float* Wih00 = (const float*)d_in[1];
  const float* Whh00 = (const float*)d_in[2];
  const float* bih00 = (const float*)d_in[3];
  const float* bhh00 = (const float*)d_in[4];
  const float* Wih01 = (const float*)d_in[5];
  const float* Whh01 = (const float*)d_in[6];
  const float* bih01 = (const float*)d_in[7];
  const float* bhh01 = (const float*)d_in[8];
  const float* Wih10 = (const float*)d_in[9];
  const float* Whh10 = (const float*)d_in[10];
  const float* bih10 = (const float*)d_in[11];
  const float* bhh10 = (const float*)d_in[12];
  const float* Wih11 = (const float*)d_in[13];
  const float* Whh11 = (const float*)d_in[14];
  const float* bih11 = (const float*)d_in[15];
  const float* bhh11 = (const float*)d_in[16];
  const float* W1 = (const float*)d_in[17];
  const float* b1 = (const float*)d_in[18];
  const float* W2 = (const float*)d_in[19];
  const float* b2 = (const float*)d_in[20];
  float* out = (float*)d_out;

  char* ws = (char*)d_ws;
  float* xg_fw = (float*)ws;                          // 64 MB  [B,T,512]
  float* xg_bw = (float*)(ws + ((size_t)64 << 20));   // 64 MB  [B,T,512]
  float* buf   = (float*)(ws + ((size_t)128 << 20));  // 32 MB  [B,T,256]

  const int M = 64 * 512;  // 32768 rows

  // ---- layer 0 ----
  gemm_mfma<0><<<dim3(M / 128, 8), 256, 0, stream>>>(
      x, Wih00, bih00, bhh00, xg_fw, M, 512, 64);
  gemm_mfma<0><<<dim3(M / 128, 8), 256, 0, stream>>>(
      x, Wih01, bih01, bhh01, xg_bw, M, 512, 64);
  lstm_seq2<<<dim3(64, 2), 256, 0, stream>>>(xg_fw, xg_bw, Whh00, Whh01, buf);

  // ---- layer 1 ----
  gemm_mfma<0><<<dim3(M / 128, 8), 256, 0, stream>>>(
      buf, Wih10, bih10, bhh10, xg_fw, M, 512, 256);
  gemm_mfma<0><<<dim3(M / 128, 8), 256, 0, stream>>>(
      buf, Wih11, bih11, bhh11, xg_bw, M, 512, 256);
  lstm_seq2<<<dim3(64, 2), 256, 0, stream>>>(xg_fw, xg_bw, Whh10, Whh11, buf);

  // ---- head ----
  gemm_mfma<1><<<dim3(M / 128, 4), 256, 0, stream>>>(
      buf, W1, b1, nullptr, xg_fw, M, 256, 256);
  gemm_mfma<2><<<dim3(M / 128, 1), 256, 0, stream>>>(
      xg_fw, W2, b2, nullptr, out, M, 64, 256);
}

// Round 7
// 712.083 us; speedup vs baseline: 2.5334x; 1.0926x over previous
//
#include <hip/hip_runtime.h>
#include <hip/hip_bf16.h>
#include <hip/hip_fp16.h>

typedef _Float16 h2vec __attribute__((ext_vector_type(2)));
typedef _Float16 f16x8 __attribute__((ext_vector_type(8)));
typedef float f32x4 __attribute__((ext_vector_type(4)));

static __device__ __forceinline__ float fast_sigmoid(float x) {
  return __builtin_amdgcn_rcpf(1.f + __expf(-x));
}
static __device__ __forceinline__ float fast_tanh(float x) {
  return 1.f - 2.f * __builtin_amdgcn_rcpf(__expf(2.f * x) + 1.f);
}
static __device__ __forceinline__ float fdot2u(unsigned int a, unsigned int b, float c) {
#if __has_builtin(__builtin_amdgcn_fdot2)
  return __builtin_amdgcn_fdot2(__builtin_bit_cast(h2vec, a),
                                __builtin_bit_cast(h2vec, b), c, false);
#else
  h2vec av = __builtin_bit_cast(h2vec, a);
  h2vec bv = __builtin_bit_cast(h2vec, b);
  return c + (float)av[0] * (float)bv[0] + (float)av[1] * (float)bv[1];
#endif
}
template<int CTRL>
static __device__ __forceinline__ float dpp_add(float v) {
  int x = __builtin_bit_cast(int, v);
  int y = __builtin_amdgcn_update_dpp(0, x, CTRL, 0xF, 0xF, true);
  return v + __builtin_bit_cast(float, y);
}
template<int CTRL>
static __device__ __forceinline__ float dpp_mov(float v) {
  int x = __builtin_bit_cast(int, v);
  int y = __builtin_amdgcn_update_dpp(0, x, CTRL, 0xF, 0xF, true);
  return __builtin_bit_cast(float, y);
}

// ---------------------------------------------------------------------------
// f16-MFMA GEMM with fused f32->f16 staging and bias+activation epilogue.
// (unchanged from round 6 — proven: ~150 us aggregate, 0 bank conflicts)
// C[M,N] = act(A[M,K] @ W[N,K]^T + bias),  A,W,C fp32 in HBM.
// MODE 0: val + b0[n] + b1[n]; MODE 1: relu(val + b0[n]); MODE 2: tanh(val + b0[n])
// ---------------------------------------------------------------------------
template<int MODE>
__global__ __launch_bounds__(256) void gemm_mfma(
    const float* __restrict__ A, const float* __restrict__ W,
    const float* __restrict__ b0, const float* __restrict__ b1,
    float* __restrict__ C, int M, int N, int K) {
  __shared__ __align__(16) unsigned char As[128 * 128];  // 128 rows x 128B
  __shared__ __align__(16) unsigned char Bs[64 * 128];   // 64 rows x 128B
  const int tid = threadIdx.x;
  const int wave = tid >> 6, l = tid & 63;
  const int wm = wave >> 1, wn = wave & 1;
  const int m0 = blockIdx.x * 128, n0 = blockIdx.y * 64;
  const int lrow = l & 15, lq = l >> 4;

  f32x4 acc[4][2] = {};

  const int arow = tid >> 1, akc = (tid & 1) * 32;   // A loader: 32 f32/thread
  const int brow = tid >> 2, bkc = (tid & 3) * 16;   // B loader: 16 f32/thread

  for (int k0 = 0; k0 < K; k0 += 64) {
    {
      const float* src = A + (size_t)(m0 + arow) * K + k0 + akc;
#pragma unroll
      for (int u = 0; u < 4; ++u) {
        float4 v0 = *reinterpret_cast<const float4*>(src + u * 8);
        float4 v1 = *reinterpret_cast<const float4*>(src + u * 8 + 4);
        f16x8 h;
        h[0] = (_Float16)v0.x; h[1] = (_Float16)v0.y;
        h[2] = (_Float16)v0.z; h[3] = (_Float16)v0.w;
        h[4] = (_Float16)v1.x; h[5] = (_Float16)v1.y;
        h[6] = (_Float16)v1.z; h[7] = (_Float16)v1.w;
        const int kbyte = (akc + u * 8) * 2;
        *reinterpret_cast<f16x8*>(&As[arow * 128 + (kbyte ^ ((arow & 7) << 4))]) = h;
      }
    }
    {
      const float* src = W + (size_t)(n0 + brow) * K + k0 + bkc;
#pragma unroll
      for (int u = 0; u < 2; ++u) {
        float4 v0 = *reinterpret_cast<const float4*>(src + u * 8);
        float4 v1 = *reinterpret_cast<const float4*>(src + u * 8 + 4);
        f16x8 h;
        h[0] = (_Float16)v0.x; h[1] = (_Float16)v0.y;
        h[2] = (_Float16)v0.z; h[3] = (_Float16)v0.w;
        h[4] = (_Float16)v1.x; h[5] = (_Float16)v1.y;
        h[6] = (_Float16)v1.z; h[7] = (_Float16)v1.w;
        const int kbyte = (bkc + u * 8) * 2;
        *reinterpret_cast<f16x8*>(&Bs[brow * 128 + (kbyte ^ ((brow & 7) << 4))]) = h;
      }
    }
    __syncthreads();

#pragma unroll
    for (int kk = 0; kk < 64; kk += 32) {
      const int kbyte = (kk + lq * 8) * 2;
      f16x8 af[4], bf[2];
#pragma unroll
      for (int mt = 0; mt < 4; ++mt) {
        const int row = wm * 64 + mt * 16 + lrow;
        af[mt] = *reinterpret_cast<const f16x8*>(
            &As[row * 128 + (kbyte ^ ((row & 7) << 4))]);
      }
#pragma unroll
      for (int nt = 0; nt < 2; ++nt) {
        const int row = wn * 32 + nt * 16 + lrow;
        bf[nt] = *reinterpret_cast<const f16x8*>(
            &Bs[row * 128 + (kbyte ^ ((row & 7) << 4))]);
      }
#pragma unroll
      for (int mt = 0; mt < 4; ++mt)
#pragma unroll
        for (int nt = 0; nt < 2; ++nt)
          acc[mt][nt] = __builtin_amdgcn_mfma_f32_16x16x32_f16(
              af[mt], bf[nt], acc[mt][nt], 0, 0, 0);
    }
    __syncthreads();
  }

#pragma unroll
  for (int nt = 0; nt < 2; ++nt) {
    const int n = n0 + wn * 32 + nt * 16 + lrow;
    float bias = 0.f;
    if (MODE == 0) bias = b0[n] + b1[n];
    else bias = b0[n];
#pragma unroll
    for (int mt = 0; mt < 4; ++mt) {
#pragma unroll
      for (int r = 0; r < 4; ++r) {
        const int m = m0 + wm * 64 + mt * 16 + lq * 4 + r;
        float val = acc[mt][nt][r] + bias;
        if (MODE == 1) val = fmaxf(val, 0.f);
        if (MODE == 2) val = fast_tanh(val);
        C[(size_t)m * N + n] = val;
      }
    }
  }
}

// ---------------------------------------------------------------------------
// LSTM recurrence, v5. v4 structure (512 thr/block, one (batch,dir) per
// block, 64 dot2/lane, quad DPP reduce, one activation/lane) PLUS:
//  - raw s_barrier with lgkmcnt(0)-only wait: xg global loads stay in
//    flight ACROSS barriers (no vmcnt(0) drain on the step chain).
//  - unroll-2 register rotation (xva/xvb): each xg load is issued ~1.7
//    steps before its consumption, no copy-induced waits.
// ---------------------------------------------------------------------------
__global__ __launch_bounds__(512, 2) void lstm_seq5(
    const float* __restrict__ xg_f, const float* __restrict__ xg_b,
    const float* __restrict__ Whh_f, const float* __restrict__ Whh_b,
    float* __restrict__ out) {
  const int b = blockIdx.x;
  const int dir = blockIdx.y;
  const int tid = threadIdx.x;
  const int j = tid >> 2;   // unit 0..127
  const int kq = tid & 3;   // k quarter
  const float* __restrict__ xg  = dir ? xg_b : xg_f;
  const float* __restrict__ Whh = dir ? Whh_b : Whh_f;

  __shared__ unsigned int hbuf[2][64];  // [buf][dword]: h as f16 pairs

  // Weights: w[g][kk] = f16x2 of row (g*128+j), k = kq*32 + 2*kk, +1
  unsigned int w[4][16];
#pragma unroll
  for (int g = 0; g < 4; ++g) {
    const float4* wr = reinterpret_cast<const float4*>(
        Whh + (size_t)(g * 128 + j) * 128 + kq * 32);
#pragma unroll
    for (int q = 0; q < 8; ++q) {
      float4 v = wr[q];
      __half2 p0 = __floats2half2_rn(v.x, v.y);
      __half2 p1 = __floats2half2_rn(v.z, v.w);
      w[g][2 * q]     = __builtin_bit_cast(unsigned int, p0);
      w[g][2 * q + 1] = __builtin_bit_cast(unsigned int, p1);
    }
  }

  if (tid < 128) hbuf[tid >> 6][tid & 63] = 0u;
  float c = 0.f;
  __syncthreads();

  const int tt0 = dir ? 511 : 0;
  const int stp = dir ? -1 : 1;
  const size_t base = (size_t)b * 512 * 512;
  const int xidx = kq * 128 + j;

  float xva = xg[base + (size_t)tt0 * 512 + xidx];          // for t=0
  float xvb = xg[base + (size_t)(tt0 + stp) * 512 + xidx];  // for t=1

  auto step = [&](int t, unsigned int* rbuf, unsigned int* wbuf, float& xcur)
      __attribute__((always_inline)) {
    const int tt = tt0 + stp * t;

    // read my h quarter: 4 x ds_read_b128, broadcast among 16 lanes each
    const uint4* hc = reinterpret_cast<const uint4*>(&rbuf[kq * 16]);
    uint4 q0 = hc[0], q1 = hc[1], q2 = hc[2], q3 = hc[3];
    unsigned int ha[16];
    ha[0] = q0.x; ha[1] = q0.y; ha[2] = q0.z; ha[3] = q0.w;
    ha[4] = q1.x; ha[5] = q1.y; ha[6] = q1.z; ha[7] = q1.w;
    ha[8] = q2.x; ha[9] = q2.y; ha[10] = q2.z; ha[11] = q2.w;
    ha[12] = q3.x; ha[13] = q3.y; ha[14] = q3.z; ha[15] = q3.w;

    float acc[4] = {0.f, 0.f, 0.f, 0.f};
#pragma unroll
    for (int kk = 0; kk < 16; ++kk) {
#pragma unroll
      for (int g = 0; g < 4; ++g)
        acc[g] = fdot2u(w[g][kk], ha[kk], acc[g]);
    }

    // quad allreduce
#pragma unroll
    for (int g = 0; g < 4; ++g) {
      float a = acc[g];
      a = dpp_add<0xB1>(a);  // xor 1
      a = dpp_add<0x4E>(a);  // xor 2
      acc[g] = a;
    }

    // lane kq activates gate kq
    float a = acc[0];
    a = (kq == 1) ? acc[1] : a;
    a = (kq == 2) ? acc[2] : a;
    a = (kq == 3) ? acc[3] : a;
    a += xcur;

    // prefetch xg for t+2 into the SAME register (consumed 2 steps later;
    // stays in flight across the raw barriers below)
    {
      const int t2 = t + 2;
      const int tt2 = (t2 < 512) ? (tt0 + stp * t2) : tt0;
      xcur = xg[base + (size_t)tt2 * 512 + xidx];
    }

    const float xs = (kq == 2) ? 2.f * a : a;
    const float y = fast_sigmoid(xs);
    const float act = (kq == 2) ? 2.f * y - 1.f : y;

    const float gi = dpp_mov<0x00>(act);
    const float gf = dpp_mov<0x55>(act);
    const float gg = dpp_mov<0xAA>(act);
    const float go = dpp_mov<0xFF>(act);

    c = gf * c + gi * gg;
    const float h = go * (2.f * fast_sigmoid(2.f * c) - 1.f);

    if (kq == 0) {  // h[j] -> next step's buffer (f16)
      unsigned short us = __builtin_bit_cast(unsigned short, (_Float16)h);
      reinterpret_cast<unsigned short*>(wbuf)[j] = us;
    }
    if (kq == 1) {  // h[j] -> global out
      out[((size_t)b * 512 + tt) * 256 + dir * 128 + j] = h;
    }

    // raw barrier: only LDS must be visible; vmem stays in flight.
    asm volatile("s_waitcnt lgkmcnt(0)" ::: "memory");
    __builtin_amdgcn_s_barrier();
    asm volatile("" ::: "memory");
  };

  for (int it = 0; it < 256; ++it) {
    step(2 * it,     hbuf[0], hbuf[1], xva);
    step(2 * it + 1, hbuf[1], hbuf[0], xvb);
  }
}

// ---------------------------------------------------------------------------
// Launcher
// ---------------------------------------------------------------------------
extern "C" void kernel_launch(void* const* d_in, const int* in_sizes, int n_in,
                              void* d_out, int out_size, void* d_ws, size_t ws_size,
                              hipStream_t stream) {
  (void)in_sizes; (void)n_in; (void)out_size; (void)ws_size;

  const float* x     = (const float*)d_in[0];
  const float* Wih00 = (const float*)d_in[1];
  const float* Whh00 = (const float*)d_in[2];
  const float* bih00 = (const float*)d_in[3];
  const float* bhh00 = (const float*)d_in[4];
  const float* Wih01 = (const float*)d_in[5];
  const float* Whh01 = (const float*)d_in[6];
  const float* bih01 = (const float*)d_in[7];
  const float* bhh01 = (const float*)d_in[8];
  const float* Wih10 = (const float*)d_in[9];
  const float* Whh10 = (const float*)d_in[10];
  const float* bih10 = (const float*)d_in[11];
  const float* bhh10 = (const float*)d_in[12];
  const float* Wih11 = (const float*)d_in[13];
  const float* Whh11 = (const float*)d_in[14];
  const float* bih11 = (const float*)d_in[15];
  const float* bhh11 = (const float*)d_in[16];
  const float* W1 = (const float*)d_in[17];
  const float* b1 = (const float*)d_in[18];
  const float* W2 = (const float*)d_in[19];
  const float* b2 = (const float*)d_in[20];
  float* out = (float*)d_out;

  char* ws = (char*)d_ws;
  float* xg_fw = (float*)ws;                          // 64 MB  [B,T,512]
  float* xg_bw = (float*)(ws + ((size_t)64 << 20));   // 64 MB  [B,T,512]
  float* buf   = (float*)(ws + ((size_t)128 << 20));  // 32 MB  [B,T,256]

  const int M = 64 * 512;  // 32768 rows

  // ---- layer 0 ----
  gemm_mfma<0><<<dim3(M / 128, 8), 256, 0, stream>>>(
      x, Wih00, bih00, bhh00, xg_fw, M, 512, 64);
  gemm_mfma<0><<<dim3(M / 128, 8), 256, 0, stream>>>(
      x, Wih01, bih01, bhh01, xg_bw, M, 512, 64);
  lstm_seq5<<<dim3(64, 2), 512, 0, stream>>>(xg_fw, xg_bw, Whh00, Whh01, buf);

  // ---- layer 1 ----
  gemm_mfma<0><<<dim3(M / 128, 8), 256, 0, stream>>>(
      buf, Wih10, bih10, bhh10, xg_fw, M, 512, 256);
  gemm_mfma<0><<<dim3(M / 128, 8), 256, 0, stream>>>(
      buf, Wih11, bih11, bhh11, xg_bw, M, 512, 256);
  lstm_seq5<<<dim3(64, 2), 512, 0, stream>>>(xg_fw, xg_bw, Whh10, Whh11, buf);

  // ---- head ----
  gemm_mfma<1><<<dim3(M / 128, 4), 256, 0, stream>>>(
      buf, W1, b1, nullptr, xg_fw, M, 256, 256);
  gemm_mfma<2><<<dim3(M / 128, 1), 256, 0, stream>>>(
      xg_fw, W2, b2, nullptr, out, M, 64, 256);
}